// Round 10
// baseline (401.947 us; speedup 1.0000x reference)
//
#include <hip/hip_runtime.h>
#include <hip/hip_bf16.h>

typedef float f32x4 __attribute__((ext_vector_type(4)));
typedef __bf16 bf16x4 __attribute__((ext_vector_type(4)));
typedef __bf16 bf16x8 __attribute__((ext_vector_type(8)));

__device__ __forceinline__ void gld_lds16(const void* g, void* l) {
  __builtin_amdgcn_global_load_lds((const __attribute__((address_space(1))) void*)g,
                                   (__attribute__((address_space(3))) void*)l, 16, 0, 0);
}

// ---------------------------------------------------------------------------
__global__ void cvt_f32_bf16(const float* __restrict__ in, __bf16* __restrict__ out,
                             int n8) {
  int idx = blockIdx.x * blockDim.x + threadIdx.x;
  if (idx >= n8) return;
  f32x4 a = *(const f32x4*)(in + (size_t)idx * 8);
  f32x4 b = *(const f32x4*)(in + (size_t)idx * 8 + 4);
  bf16x8 o;
#pragma unroll
  for (int j = 0; j < 4; ++j) { o[j] = (__bf16)a[j]; o[4 + j] = (__bf16)b[j]; }
  *(bf16x8*)(out + (size_t)idx * 8) = o;
}

// ---------------------------------------------------------------------------
__global__ void build_trig(float* __restrict__ trig) {
  int idx = blockIdx.x * blockDim.x + threadIdx.x;
  if (idx >= 2048 * 64) return;
  int i = idx & 63, s = idx >> 6;
  float ang = (float)s * powf(10000.0f, -(float)i * (1.0f / 64.0f));
  float sn, cs;
  sincosf(ang, &sn, &cs);
  trig[idx * 2] = cs;
  trig[idx * 2 + 1] = sn;
}

// ---------------------------------------------------------------------------
__global__ void rope_bf16(__bf16* __restrict__ T, const float* __restrict__ trig,
                          int stride, int nh_mask, int nh_shift, float mul, int total) {
  int idx = blockIdx.x * blockDim.x + threadIdx.x;
  if (idx >= total) return;
  int i = idx & 63;
  int h = (idx >> 6) & nh_mask;
  int s = idx >> (6 + nh_shift);
  float cs = trig[(s * 64 + i) * 2];
  float sn = trig[(s * 64 + i) * 2 + 1];
  __bf16* p = T + (size_t)s * stride + h * 128 + 2 * i;
  float e = (float)p[0], o = (float)p[1];
  p[0] = (__bf16)((e * cs - o * sn) * mul);
  p[1] = (__bf16)((e * sn + o * cs) * mul);
}

// ---------------------------------------------------------------------------
__global__ __launch_bounds__(256) void transpose_v(const __bf16* __restrict__ KVb,
                                                   __bf16* __restrict__ Vt) {
  __shared__ __bf16 T[64][72];
  const int tid = threadIdx.x;
  const int s0 = blockIdx.x * 64, d0 = blockIdx.y * 64;
  const int r = tid >> 3, c8 = (tid & 7) * 8;
#pragma unroll
  for (int i = 0; i < 2; ++i) {
    int row = i * 32 + r;
    *(bf16x8*)&T[row][c8] = *(const bf16x8*)&KVb[(size_t)(s0 + row) * 2048 + 1024 + d0 + c8];
  }
  __syncthreads();
#pragma unroll
  for (int i = 0; i < 2; ++i) {
    int drow = i * 32 + r;
    bf16x8 o;
#pragma unroll
    for (int j = 0; j < 8; ++j) o[j] = T[c8 + j][drow];
    *(bf16x8*)&Vt[(size_t)(d0 + drow) * 2048 + s0 + c8] = o;
  }
}

// ---------------------------------------------------------------------------
// Old GEMM (kept for the KV projection, N=2048): 128-class tile, 2-barrier.
// ---------------------------------------------------------------------------
template <int BM, int BN, typename OutT>
__global__ __launch_bounds__(256) void gemm_bf16(const __bf16* __restrict__ A,
                                                 const __bf16* __restrict__ B0,
                                                 const __bf16* __restrict__ B1,
                                                 int Nsplit, OutT* __restrict__ C,
                                                 int M, int N, int K) {
  constexpr int MI = BM / 32, NJ = BN / 32;
  constexpr int RA = BM / 32, RB = BN / 32;
  __shared__ __bf16 As[BM * 64] __attribute__((aligned(16)));
  __shared__ __bf16 Bs[BN * 64] __attribute__((aligned(16)));

  const int tid = threadIdx.x;
  const int lane = tid & 63;
  const int w = tid >> 6;
  const int nwg = gridDim.x * gridDim.y;
  const int orig = blockIdx.y * gridDim.x + blockIdx.x;
  const int wgid = (orig & 7) * (nwg >> 3) + (orig >> 3);
  const int m0 = (wgid % gridDim.x) * BM;
  const int n0 = (wgid / gridDim.x) * BN;
  const int li = lane & 15, lg = lane >> 4;

  const __bf16* bsrc[RB];
#pragma unroll
  for (int i = 0; i < RB; ++i) {
    int slot = i * 256 + w * 64 + lane;
    int row = slot >> 3;
    int sch = (slot & 7) ^ (row & 7);
    int n = n0 + row;
    bsrc[i] = (n < Nsplit ? B0 + (size_t)n * K : B1 + (size_t)(n - Nsplit) * K) +
              sch * 8;
  }
  const __bf16* asrc[RA];
#pragma unroll
  for (int i = 0; i < RA; ++i) {
    int slot = i * 256 + w * 64 + lane;
    int row = slot >> 3;
    int sch = (slot & 7) ^ (row & 7);
    asrc[i] = A + (size_t)(m0 + row) * K + sch * 8;
  }

  const int wr = (w >> 1) * (BM / 2);
  const int wc = (w & 1) * (BN / 2);

  f32x4 acc[MI][NJ] = {};

  for (int k0 = 0; k0 < K; k0 += 64) {
    __syncthreads();
#pragma unroll
    for (int i = 0; i < RA; ++i)
      gld_lds16(asrc[i] + k0, &As[(i * 256 + w * 64) * 8]);
#pragma unroll
    for (int i = 0; i < RB; ++i)
      gld_lds16(bsrc[i] + k0, &Bs[(i * 256 + w * 64) * 8]);
    __syncthreads();

#pragma unroll
    for (int u = 0; u < 2; ++u) {
      bf16x8 af[MI], bfr[NJ];
#pragma unroll
      for (int mi = 0; mi < MI; ++mi)
        af[mi] = *(const bf16x8*)&As[(wr + mi * 16 + li) * 64 +
                                     (((u * 4 + lg) ^ (li & 7)) * 8)];
#pragma unroll
      for (int nj = 0; nj < NJ; ++nj)
        bfr[nj] = *(const bf16x8*)&Bs[(wc + nj * 16 + li) * 64 +
                                      (((u * 4 + lg) ^ (li & 7)) * 8)];
#pragma unroll
      for (int mi = 0; mi < MI; ++mi)
#pragma unroll
        for (int nj = 0; nj < NJ; ++nj)
          acc[mi][nj] = __builtin_amdgcn_mfma_f32_16x16x32_bf16(af[mi], bfr[nj],
                                                                acc[mi][nj], 0, 0, 0);
    }
  }

  const int crow = lg * 4;
#pragma unroll
  for (int mi = 0; mi < MI; ++mi)
#pragma unroll
    for (int nj = 0; nj < NJ; ++nj)
#pragma unroll
      for (int r = 0; r < 4; ++r)
        C[(size_t)(m0 + wr + mi * 16 + crow + r) * N + (n0 + wc + nj * 16 + li)] =
            (OutT)acc[mi][nj][r];
}

// ---------------------------------------------------------------------------
// Big-projection GEMM v2 (m201-style fine phases): C = A @ B^T.
// 256x128 tile, 8 waves (2M x 4N), BK=64, THREE LDS buffers (144 KB) so
// tile t+2's staging is issued DURING tile t's compute phases (R8's coarse
// split could not: 2 buffers forbid staging while cur is read).
// 4 phases/tile: (u, m-half), each = {frag ds_reads + 1-2 stage issues ->
// barrier -> lgkmcnt(0) -> setprio(1) 8xMFMA setprio(0) -> barrier}.
// vmcnt(6) once per tile end (t+1 landed, t+2 in flight); never 0.
// 6 loads/thread/tile uniform (dummy refetch on tail) -> exact FIFO.
// ---------------------------------------------------------------------------
template <typename OutT>
__global__ __launch_bounds__(512) void gemm_bt8(const __bf16* __restrict__ A,
                                                const __bf16* __restrict__ B,
                                                OutT* __restrict__ C,
                                                int M, int N, int K) {
  __shared__ __bf16 As[3][256 * 64] __attribute__((aligned(16)));  // 96 KB
  __shared__ __bf16 Bs[3][128 * 64] __attribute__((aligned(16)));  // 48 KB

  const int tid = threadIdx.x;
  const int lane = tid & 63;
  const int w = tid >> 6;                 // 0..7
  const int nwg = gridDim.x * gridDim.y;
  const int orig = blockIdx.y * gridDim.x + blockIdx.x;
  const int wgid = (orig & 7) * (nwg >> 3) + (orig >> 3);
  const int m0 = (wgid % gridDim.x) * 256;
  const int n0 = (wgid / gridDim.x) * 128;
  const int li = lane & 15, lg = lane >> 4;

  // staging sources (T2: chunk XOR on global side, LDS linear)
  const __bf16* asrc[4];
#pragma unroll
  for (int i = 0; i < 4; ++i) {
    int slot = i * 512 + tid;
    int row = slot >> 3;                  // 0..255
    int sch = (slot & 7) ^ (row & 7);
    asrc[i] = A + (size_t)(m0 + row) * K + sch * 8;
  }
  const __bf16* bsrc[2];
#pragma unroll
  for (int i = 0; i < 2; ++i) {
    int slot = i * 512 + tid;
    int row = slot >> 3;                  // 0..127
    int sch = (slot & 7) ^ (row & 7);
    bsrc[i] = B + (size_t)(n0 + row) * K + sch * 8;
  }

  const int wm = (w >> 2) * 128;          // 0 / 128
  const int wn = (w & 3) * 32;            // 0/32/64/96

  f32x4 acc[8][2] = {};
  const int NT = K >> 6;

  // prologue: stage tiles 0 (buf0) and 1 (buf1)
#pragma unroll
  for (int i = 0; i < 4; ++i) gld_lds16(asrc[i], &As[0][(i * 512 + w * 64) * 8]);
#pragma unroll
  for (int i = 0; i < 2; ++i) gld_lds16(bsrc[i], &Bs[0][(i * 512 + w * 64) * 8]);
#pragma unroll
  for (int i = 0; i < 4; ++i) gld_lds16(asrc[i] + 64, &As[1][(i * 512 + w * 64) * 8]);
#pragma unroll
  for (int i = 0; i < 2; ++i) gld_lds16(bsrc[i] + 64, &Bs[1][(i * 512 + w * 64) * 8]);
  asm volatile("s_waitcnt vmcnt(6)" ::: "memory");   // tile 0 landed
  __builtin_amdgcn_s_barrier();
  __builtin_amdgcn_sched_barrier(0);

#pragma unroll 1
  for (int t = 0; t < NT; ++t) {
    const int cb = t % 3;
    const int nb = (t + 2) % 3;           // != cb, != (t+1)%3
    const long koff = (long)((t + 2 < NT) ? t + 2 : t) * 64;  // dummy on tail
    const __bf16* Asc = &As[cb][0];
    const __bf16* Bsc = &Bs[cb][0];
    const int kc0 = (lg ^ (li & 7)) * 8;
    const int kc1 = ((4 + lg) ^ (li & 7)) * 8;

    bf16x8 af[4], bu[2];

    // ---- phase 0: u=0, rows wm+0..63 ----
#pragma unroll
    for (int mi = 0; mi < 4; ++mi)
      af[mi] = *(const bf16x8*)&Asc[(wm + mi * 16 + li) * 64 + kc0];
#pragma unroll
    for (int nj = 0; nj < 2; ++nj)
      bu[nj] = *(const bf16x8*)&Bsc[(wn + nj * 16 + li) * 64 + kc0];
    gld_lds16(asrc[0] + koff, &As[nb][(0 * 512 + w * 64) * 8]);
    gld_lds16(asrc[1] + koff, &As[nb][(1 * 512 + w * 64) * 8]);
    __builtin_amdgcn_s_barrier();
    asm volatile("s_waitcnt lgkmcnt(0)" ::: "memory");
    __builtin_amdgcn_sched_barrier(0);
    __builtin_amdgcn_s_setprio(1);
#pragma unroll
    for (int mi = 0; mi < 4; ++mi)
#pragma unroll
      for (int nj = 0; nj < 2; ++nj)
        acc[mi][nj] = __builtin_amdgcn_mfma_f32_16x16x32_bf16(af[mi], bu[nj],
                                                              acc[mi][nj], 0, 0, 0);
    __builtin_amdgcn_s_setprio(0);
    __builtin_amdgcn_s_barrier();

    // ---- phase 1: u=0, rows wm+64..127 ----
#pragma unroll
    for (int mi = 0; mi < 4; ++mi)
      af[mi] = *(const bf16x8*)&Asc[(wm + 64 + mi * 16 + li) * 64 + kc0];
    gld_lds16(asrc[2] + koff, &As[nb][(2 * 512 + w * 64) * 8]);
    gld_lds16(asrc[3] + koff, &As[nb][(3 * 512 + w * 64) * 8]);
    __builtin_amdgcn_s_barrier();
    asm volatile("s_waitcnt lgkmcnt(0)" ::: "memory");
    __builtin_amdgcn_sched_barrier(0);
    __builtin_amdgcn_s_setprio(1);
#pragma unroll
    for (int mi = 0; mi < 4; ++mi)
#pragma unroll
      for (int nj = 0; nj < 2; ++nj)
        acc[4 + mi][nj] = __builtin_amdgcn_mfma_f32_16x16x32_bf16(af[mi], bu[nj],
                                                                  acc[4 + mi][nj], 0, 0, 0);
    __builtin_amdgcn_s_setprio(0);
    __builtin_amdgcn_s_barrier();

    // ---- phase 2: u=1, rows wm+0..63 ----
#pragma unroll
    for (int mi = 0; mi < 4; ++mi)
      af[mi] = *(const bf16x8*)&Asc[(wm + mi * 16 + li) * 64 + kc1];
#pragma unroll
    for (int nj = 0; nj < 2; ++nj)
      bu[nj] = *(const bf16x8*)&Bsc[(wn + nj * 16 + li) * 64 + kc1];
    gld_lds16(bsrc[0] + koff, &Bs[nb][(0 * 512 + w * 64) * 8]);
    __builtin_amdgcn_s_barrier();
    asm volatile("s_waitcnt lgkmcnt(0)" ::: "memory");
    __builtin_amdgcn_sched_barrier(0);
    __builtin_amdgcn_s_setprio(1);
#pragma unroll
    for (int mi = 0; mi < 4; ++mi)
#pragma unroll
      for (int nj = 0; nj < 2; ++nj)
        acc[mi][nj] = __builtin_amdgcn_mfma_f32_16x16x32_bf16(af[mi], bu[nj],
                                                              acc[mi][nj], 0, 0, 0);
    __builtin_amdgcn_s_setprio(0);
    __builtin_amdgcn_s_barrier();

    // ---- phase 3: u=1, rows wm+64..127 ----
#pragma unroll
    for (int mi = 0; mi < 4; ++mi)
      af[mi] = *(const bf16x8*)&Asc[(wm + 64 + mi * 16 + li) * 64 + kc1];
    gld_lds16(bsrc[1] + koff, &Bs[nb][(1 * 512 + w * 64) * 8]);
    __builtin_amdgcn_s_barrier();
    asm volatile("s_waitcnt lgkmcnt(0)" ::: "memory");
    __builtin_amdgcn_sched_barrier(0);
    __builtin_amdgcn_s_setprio(1);
#pragma unroll
    for (int mi = 0; mi < 4; ++mi)
#pragma unroll
      for (int nj = 0; nj < 2; ++nj)
        acc[4 + mi][nj] = __builtin_amdgcn_mfma_f32_16x16x32_bf16(af[mi], bu[nj],
                                                                  acc[4 + mi][nj], 0, 0, 0);
    __builtin_amdgcn_s_setprio(0);

    // ---- tile end: t+1 landed (t+2's 6 stay in flight) ----
    asm volatile("s_waitcnt vmcnt(6)" ::: "memory");
    __builtin_amdgcn_s_barrier();
    __builtin_amdgcn_sched_barrier(0);
  }

  // ---- epilogue: C write (C/D layout: row=lg*4+r, col=li) ----
#pragma unroll
  for (int mi = 0; mi < 8; ++mi)
#pragma unroll
    for (int nj = 0; nj < 2; ++nj)
#pragma unroll
      for (int r = 0; r < 4; ++r)
        C[(size_t)(m0 + wm + mi * 16 + lg * 4 + r) * N + (n0 + wn + nj * 16 + li)] =
            (OutT)acc[mi][nj][r];
}

// ---------------------------------------------------------------------------
// Causal GQA flash attention v6 (unchanged from R7).
// ---------------------------------------------------------------------------
__global__ __launch_bounds__(512) void attn_fwd_v6(const __bf16* __restrict__ Q,
                                                   const __bf16* __restrict__ KVb,
                                                   const __bf16* __restrict__ Vt,
                                                   __bf16* __restrict__ O) {
  const int tid = threadIdx.x;
  const int lane = tid & 63;
  const int w = tid >> 6;           // 0..7
  const int orig = blockIdx.x;
  const int chunk = orig & 7;       // XCD owns kvh group
  const int wkk = orig >> 3;        // 0..31
  const int h = chunk * 4 + (wkk & 3);
  const int pair = wkk >> 2;        // 0..7
  const int kvh = h >> 2;

  __shared__ __bf16 Ks[2][64 * 128] __attribute__((aligned(16)));   // 32 KB
  __shared__ __bf16 Vts[2][128 * 64] __attribute__((aligned(16)));  // 32 KB
  __shared__ __bf16 Ps[8][16 * 72] __attribute__((aligned(16)));    // 18 KB

  const int li = lane & 15, lg = lane >> 4;

  auto stage_k = [&](int k0, int buf) {
#pragma unroll
    for (int i = 0; i < 2; ++i) {
      int slot = i * 512 + tid;
      int row = slot >> 4;                 // 0..63 key
      int sch = (slot & 15) ^ (row & 7);
      gld_lds16(&KVb[(size_t)(k0 + row) * 2048 + kvh * 128 + sch * 8],
                &Ks[buf][(i * 512 + w * 64) * 8]);
    }
  };
  auto stage_v = [&](int k0, int buf) {
#pragma unroll
    for (int i = 0; i < 2; ++i) {
      int slot = i * 512 + tid;
      int row = slot >> 3;                 // 0..127 d
      int sch = (slot & 7) ^ (row & 7);
      gld_lds16(&Vt[(size_t)(kvh * 128 + row) * 2048 + k0 + sch * 8],
                &Vts[buf][(i * 512 + w * 64) * 8]);
    }
  };

#pragma unroll 1
  for (int pass = 0; pass < 2; ++pass) {
    const int m0 = ((pass == 0) ? (15 - pair) : pair) * 128;
    const int rbase = m0 + w * 16;        // 16 rows per wave

    bf16x8 qf[4];
    {
      const __bf16* qrow = Q + (size_t)(rbase + li) * 4096 + h * 128;
#pragma unroll
      for (int kc = 0; kc < 4; ++kc) qf[kc] = *(const bf16x8*)(qrow + kc * 32 + lg * 8);
    }

    f32x4 accO[8] = {};
    float plane = 0.f;

    const int wmax = rbase + 15;
    const int ntile = (m0 + 128) >> 6;

    __builtin_amdgcn_s_barrier();   // prev pass/tile readers done with all buffers
    stage_v(0, 0);
    stage_k(0, 0);

#pragma unroll 1
    for (int t = 0; t < ntile; ++t) {
      const int k0 = t * 64;
      const int cur = t & 1;

      __builtin_amdgcn_s_barrier();       // (A) everyone done reading buf[cur^1]
      const int nk = (t + 1 < ntile) ? k0 + 64 : 0;  // dummy keeps FIFO uniform
      stage_v(nk, cur ^ 1);
      stage_k(nk, cur ^ 1);

      asm volatile("s_waitcnt vmcnt(4)" ::: "memory");  // my K(t),V(t) landed
      __builtin_amdgcn_s_barrier();                     // (B) whole tile staged
      __builtin_amdgcn_sched_barrier(0);
      asm volatile("" ::: "memory");

      if (k0 <= wmax) {
        // ---- QK^T swapped: rows=key, cols=q ----
        f32x4 s2[4] = {};
        __builtin_amdgcn_s_setprio(1);
#pragma unroll
        for (int nt = 0; nt < 4; ++nt)
#pragma unroll
          for (int kc = 0; kc < 4; ++kc) {
            bf16x8 kf = *(const bf16x8*)&Ks[cur][(li + 16 * nt) * 128 +
                                                (((4 * kc + lg) ^ (li & 7)) * 8)];
            s2[nt] = __builtin_amdgcn_mfma_f32_16x16x32_bf16(kf, qf[kc], s2[nt], 0, 0, 0);
          }
        __builtin_amdgcn_s_setprio(0);

        // ---- static-max softmax: p = exp2(s); per-lane partial row-sum ----
        const int q = rbase + li;
        const bool needmask = (k0 + 63 > rbase);
#pragma unroll
        for (int nt = 0; nt < 4; ++nt) {
          bf16x4 pk;
#pragma unroll
          for (int r = 0; r < 4; ++r) {
            const int key = k0 + 16 * nt + lg * 4 + r;
            float v = s2[nt][r];
            if (needmask && key > q) v = -INFINITY;
            float p = exp2f(v);
            plane += p;
            pk[r] = (__bf16)p;
          }
          *(bf16x4*)&Ps[w][li * 72 + 16 * nt + lg * 4] = pk;
        }
        bf16x8 pa[2];
        pa[0] = *(const bf16x8*)&Ps[w][li * 72 + lg * 8];
        pa[1] = *(const bf16x8*)&Ps[w][li * 72 + 32 + lg * 8];

        // ---- PV ----
        __builtin_amdgcn_s_setprio(1);
#pragma unroll
        for (int dt = 0; dt < 8; ++dt)
#pragma unroll
          for (int kc = 0; kc < 2; ++kc) {
            bf16x8 vf = *(const bf16x8*)&Vts[cur][(li + 16 * dt) * 64 +
                                                 (((4 * kc + lg) ^ (li & 7)) * 8)];
            accO[dt] = __builtin_amdgcn_mfma_f32_16x16x32_bf16(pa[kc], vf, accO[dt], 0, 0, 0);
          }
        __builtin_amdgcn_s_setprio(0);
      }
    }

    // ---- epilogue: reduce plane over lg-duplicates, normalize, store ----
    {
      float sum = plane;
      sum += __shfl_xor(sum, 16);
      sum += __shfl_xor(sum, 32);   // lanes sharing li hold total for q = rbase+li
      float inv[4];
#pragma unroll
      for (int r = 0; r < 4; ++r) inv[r] = 1.0f / __shfl(sum, lg * 4 + r);
#pragma unroll
      for (int dt = 0; dt < 8; ++dt)
#pragma unroll
        for (int r = 0; r < 4; ++r)
          O[(size_t)(rbase + lg * 4 + r) * 4096 + h * 128 + dt * 16 + li] =
              (__bf16)(accO[dt][r] * inv[r]);
    }
  }
}

// ---------------------------------------------------------------------------
extern "C" void kernel_launch(void* const* d_in, const int* in_sizes, int n_in,
                              void* d_out, int out_size, void* d_ws, size_t ws_size,
                              hipStream_t stream) {
  const float* x  = (const float*)d_in[0];
  const float* wq = (const float*)d_in[1];
  const float* wk = (const float*)d_in[2];
  const float* wv = (const float*)d_in[3];
  const float* wo = (const float*)d_in[4];
  float* out = (float*)d_out;

  const int S = 2048, D = 4096;
  char* ws = (char*)d_ws;
  __bf16* xb  = (__bf16*)ws;                      // 16 MB (reused as AOb)
  __bf16* Qb  = (__bf16*)(ws + 16777216);         // 16 MB
  __bf16* KVb = (__bf16*)(ws + 33554432);         //  8 MB [2048][2048] K|V
  __bf16* Vt  = (__bf16*)(ws + 41943040);         //  4 MB [1024][2048]
  __bf16* wb  = (__bf16*)(ws + 46137344);         // 32 MB weight scratch
  float*  trig = (float*)(ws + 79691776);         //  1 MB
  __bf16* AOb = xb;

  // 1/sqrt(128) * log2(e): scores in log2 domain -> p = exp2(s)
  const float qscale = 0.08838834764831845f * 1.4426950408889634f;

  cvt_f32_bf16<<<(S * D / 8 + 255) / 256, 256, 0, stream>>>(x, xb, S * D / 8);
  cvt_f32_bf16<<<(D * D / 8 + 255) / 256, 256, 0, stream>>>(wq, wb, D * D / 8);
  gemm_bt8<__bf16><<<dim3(8, 32), 512, 0, stream>>>(xb, wb, Qb, S, D, D);

  cvt_f32_bf16<<<(1024 * D / 8 + 255) / 256, 256, 0, stream>>>(wk, wb, 1024 * D / 8);
  cvt_f32_bf16<<<(1024 * D / 8 + 255) / 256, 256, 0, stream>>>(wv, wb + (size_t)1024 * D,
                                                               1024 * D / 8);
  gemm_bf16<64, 128, __bf16><<<dim3(32, 16), 256, 0, stream>>>(
      xb, wb, wb + (size_t)1024 * D, 1024, KVb, S, 2048, D);

  build_trig<<<(2048 * 64 + 255) / 256, 256, 0, stream>>>(trig);
  rope_bf16<<<(S * 32 * 64 + 255) / 256, 256, 0, stream>>>(Qb, trig, 4096, 31, 5,
                                                           qscale, S * 32 * 64);
  rope_bf16<<<(S * 8 * 64 + 255) / 256, 256, 0, stream>>>(KVb, trig, 2048, 7, 3,
                                                          1.0f, S * 8 * 64);
  transpose_v<<<dim3(32, 16), 256, 0, stream>>>(KVb, Vt);

  attn_fwd_v6<<<256, 512, 0, stream>>>(Qb, KVb, Vt, AOb);

  cvt_f32_bf16<<<(D * D / 8 + 255) / 256, 256, 0, stream>>>(wo, wb, D * D / 8);
  gemm_bt8<float><<<dim3(8, 32), 512, 0, stream>>>(AOb, wb, out, S, D, D);
}

// Round 11
// 344.656 us; speedup vs baseline: 1.1662x; 1.1662x over previous
//
#include <hip/hip_runtime.h>
#include <hip/hip_bf16.h>

typedef float f32x2 __attribute__((ext_vector_type(2)));
typedef float f32x4 __attribute__((ext_vector_type(4)));
typedef __bf16 bf16x4 __attribute__((ext_vector_type(4)));
typedef __bf16 bf16x8 __attribute__((ext_vector_type(8)));

__device__ __forceinline__ void gld_lds16(const void* g, void* l) {
  __builtin_amdgcn_global_load_lds((const __attribute__((address_space(1))) void*)g,
                                   (__attribute__((address_space(3))) void*)l, 16, 0, 0);
}

// ---------------------------------------------------------------------------
__global__ void cvt_f32_bf16(const float* __restrict__ in, __bf16* __restrict__ out,
                             int n8) {
  int idx = blockIdx.x * blockDim.x + threadIdx.x;
  if (idx >= n8) return;
  f32x4 a = *(const f32x4*)(in + (size_t)idx * 8);
  f32x4 b = *(const f32x4*)(in + (size_t)idx * 8 + 4);
  bf16x8 o;
#pragma unroll
  for (int j = 0; j < 4; ++j) { o[j] = (__bf16)a[j]; o[4 + j] = (__bf16)b[j]; }
  *(bf16x8*)(out + (size_t)idx * 8) = o;
}

// ---------------------------------------------------------------------------
__global__ void build_trig(float* __restrict__ trig) {
  int idx = blockIdx.x * blockDim.x + threadIdx.x;
  if (idx >= 2048 * 64) return;
  int i = idx & 63, s = idx >> 6;
  float ang = (float)s * powf(10000.0f, -(float)i * (1.0f / 64.0f));
  float sn, cs;
  sincosf(ang, &sn, &cs);
  trig[idx * 2] = cs;
  trig[idx * 2 + 1] = sn;
}

// ---------------------------------------------------------------------------
// RoPE in-place on bf16 (used for K only; Q-rope is folded into attention).
// ---------------------------------------------------------------------------
__global__ void rope_bf16(__bf16* __restrict__ T, const float* __restrict__ trig,
                          int stride, int nh_mask, int nh_shift, float mul, int total) {
  int idx = blockIdx.x * blockDim.x + threadIdx.x;
  if (idx >= total) return;
  int i = idx & 63;
  int h = (idx >> 6) & nh_mask;
  int s = idx >> (6 + nh_shift);
  float cs = trig[(s * 64 + i) * 2];
  float sn = trig[(s * 64 + i) * 2 + 1];
  __bf16* p = T + (size_t)s * stride + h * 128 + 2 * i;
  float e = (float)p[0], o = (float)p[1];
  p[0] = (__bf16)((e * cs - o * sn) * mul);
  p[1] = (__bf16)((e * sn + o * cs) * mul);
}

// ---------------------------------------------------------------------------
__global__ __launch_bounds__(256) void transpose_v(const __bf16* __restrict__ KVb,
                                                   __bf16* __restrict__ Vt) {
  __shared__ __bf16 T[64][72];
  const int tid = threadIdx.x;
  const int s0 = blockIdx.x * 64, d0 = blockIdx.y * 64;
  const int r = tid >> 3, c8 = (tid & 7) * 8;
#pragma unroll
  for (int i = 0; i < 2; ++i) {
    int row = i * 32 + r;
    *(bf16x8*)&T[row][c8] = *(const bf16x8*)&KVb[(size_t)(s0 + row) * 2048 + 1024 + d0 + c8];
  }
  __syncthreads();
#pragma unroll
  for (int i = 0; i < 2; ++i) {
    int drow = i * 32 + r;
    bf16x8 o;
#pragma unroll
    for (int j = 0; j < 8; ++j) o[j] = T[c8 + j][drow];
    *(bf16x8*)&Vt[(size_t)(d0 + drow) * 2048 + s0 + c8] = o;
  }
}

// ---------------------------------------------------------------------------
// GEMM  C[M][N] = A[M][K] @ B[N][K]^T, bf16 in, OutT out.  (R7-proven:
// 128-class tile, BK=64, global_load_lds + T2 source-XOR swizzle, 2 barriers,
// 2 blocks/CU implicit overlap, bijective XCD swizzle.)
// ---------------------------------------------------------------------------
template <int BM, int BN, typename OutT>
__global__ __launch_bounds__(256) void gemm_bf16(const __bf16* __restrict__ A,
                                                 const __bf16* __restrict__ B0,
                                                 const __bf16* __restrict__ B1,
                                                 int Nsplit, OutT* __restrict__ C,
                                                 int M, int N, int K) {
  constexpr int MI = BM / 32, NJ = BN / 32;
  constexpr int RA = BM / 32, RB = BN / 32;
  __shared__ __bf16 As[BM * 64] __attribute__((aligned(16)));
  __shared__ __bf16 Bs[BN * 64] __attribute__((aligned(16)));

  const int tid = threadIdx.x;
  const int lane = tid & 63;
  const int w = tid >> 6;
  const int nwg = gridDim.x * gridDim.y;
  const int orig = blockIdx.y * gridDim.x + blockIdx.x;
  const int wgid = (orig & 7) * (nwg >> 3) + (orig >> 3);
  const int m0 = (wgid % gridDim.x) * BM;
  const int n0 = (wgid / gridDim.x) * BN;
  const int li = lane & 15, lg = lane >> 4;

  const __bf16* bsrc[RB];
#pragma unroll
  for (int i = 0; i < RB; ++i) {
    int slot = i * 256 + w * 64 + lane;
    int row = slot >> 3;
    int sch = (slot & 7) ^ (row & 7);
    int n = n0 + row;
    bsrc[i] = (n < Nsplit ? B0 + (size_t)n * K : B1 + (size_t)(n - Nsplit) * K) +
              sch * 8;
  }
  const __bf16* asrc[RA];
#pragma unroll
  for (int i = 0; i < RA; ++i) {
    int slot = i * 256 + w * 64 + lane;
    int row = slot >> 3;
    int sch = (slot & 7) ^ (row & 7);
    asrc[i] = A + (size_t)(m0 + row) * K + sch * 8;
  }

  const int wr = (w >> 1) * (BM / 2);
  const int wc = (w & 1) * (BN / 2);

  f32x4 acc[MI][NJ] = {};

  for (int k0 = 0; k0 < K; k0 += 64) {
    __syncthreads();
#pragma unroll
    for (int i = 0; i < RA; ++i)
      gld_lds16(asrc[i] + k0, &As[(i * 256 + w * 64) * 8]);
#pragma unroll
    for (int i = 0; i < RB; ++i)
      gld_lds16(bsrc[i] + k0, &Bs[(i * 256 + w * 64) * 8]);
    __syncthreads();

#pragma unroll
    for (int u = 0; u < 2; ++u) {
      bf16x8 af[MI], bfr[NJ];
#pragma unroll
      for (int mi = 0; mi < MI; ++mi)
        af[mi] = *(const bf16x8*)&As[(wr + mi * 16 + li) * 64 +
                                     (((u * 4 + lg) ^ (li & 7)) * 8)];
#pragma unroll
      for (int nj = 0; nj < NJ; ++nj)
        bfr[nj] = *(const bf16x8*)&Bs[(wc + nj * 16 + li) * 64 +
                                      (((u * 4 + lg) ^ (li & 7)) * 8)];
#pragma unroll
      for (int mi = 0; mi < MI; ++mi)
#pragma unroll
        for (int nj = 0; nj < NJ; ++nj)
          acc[mi][nj] = __builtin_amdgcn_mfma_f32_16x16x32_bf16(af[mi], bfr[nj],
                                                                acc[mi][nj], 0, 0, 0);
    }
  }

  const int crow = lg * 4;
#pragma unroll
  for (int mi = 0; mi < MI; ++mi)
#pragma unroll
    for (int nj = 0; nj < NJ; ++nj)
#pragma unroll
      for (int r = 0; r < 4; ++r)
        C[(size_t)(m0 + wr + mi * 16 + crow + r) * N + (n0 + wc + nj * 16 + li)] =
            (OutT)acc[mi][nj][r];
}

// ---------------------------------------------------------------------------
// Causal GQA flash attention v7.
// 4 waves / 64 q-rows per block; LDS 57KB (K dbuf + V single + Ps) -> TWO
// independent blocks per CU (implicit inter-block overlap; this is what the
// 8-wave/86KB v6 structurally lacked). Grid 1024, longest-first (mb
// descending ~ LPT backfill); kvh == XCD so each XCD's 1MB K/V panel is
// L2-resident. Counted vmcnt per tile: 8 issues (V:4, K(t+1):4);
// vmcnt(8) before QK (K(t) done), vmcnt(4) before PV (V done); never 0.
// Q-RoPE + scale*log2e folded into the prologue load (in-register; each
// lane's bf16x8 holds 4 complete even/odd dim pairs).
// ---------------------------------------------------------------------------
__global__ __launch_bounds__(256) void attn_fwd_v7(const __bf16* __restrict__ Q,
                                                   const __bf16* __restrict__ KVb,
                                                   const __bf16* __restrict__ Vt,
                                                   const float* __restrict__ trig,
                                                   __bf16* __restrict__ O) {
  const int tid = threadIdx.x;
  const int lane = tid & 63;
  const int w = tid >> 6;           // 0..3
  const int bid = blockIdx.x;
  const int xcd = bid & 7;
  const int r9 = bid >> 3;          // 0..127 within XCD
  const int h = xcd * 4 + (r9 & 3);
  const int mb = 31 - (r9 >> 2);    // 31..0, longest blocks first
  const int kvh = h >> 2;           // == xcd
  const int m0 = mb * 64;
  const int rbase = m0 + w * 16;

  __shared__ __bf16 Ks[2][64 * 128] __attribute__((aligned(16)));  // 32 KB
  __shared__ __bf16 Vs[128 * 64] __attribute__((aligned(16)));     // 16 KB
  __shared__ __bf16 Ps[4][16 * 72] __attribute__((aligned(16)));   //  9 KB

  const int li = lane & 15, lg = lane >> 4;
  const float qscale = 0.08838834764831845f * 1.4426950408889634f;  // 1/sqrt(128)*log2e

  auto stage_k = [&](int k0, int buf) {
#pragma unroll
    for (int i = 0; i < 4; ++i) {
      int slot = i * 256 + tid;
      int row = slot >> 4;                 // 0..63 key
      int sch = (slot & 15) ^ (row & 7);
      gld_lds16(&KVb[(size_t)(k0 + row) * 2048 + kvh * 128 + sch * 8],
                &Ks[buf][(i * 256 + w * 64) * 8]);
    }
  };
  auto stage_v = [&](int k0) {
#pragma unroll
    for (int i = 0; i < 4; ++i) {
      int slot = i * 256 + tid;
      int row = slot >> 3;                 // 0..127 d
      int sch = (slot & 7) ^ (row & 7);
      gld_lds16(&Vt[(size_t)(kvh * 128 + row) * 2048 + k0 + sch * 8],
                &Vs[(i * 256 + w * 64) * 8]);
    }
  };

  // ---- prologue: Q load + in-register RoPE + scale (lane q-row s=rbase+li)
  const int s = rbase + li;
  bf16x8 qf[4];
  {
    const __bf16* qrow = Q + (size_t)s * 4096 + h * 128;
#pragma unroll
    for (int kc = 0; kc < 4; ++kc) {
      bf16x8 raw = *(const bf16x8*)(qrow + kc * 32 + lg * 8);
#pragma unroll
      for (int jj = 0; jj < 4; ++jj) {
        int i = kc * 16 + lg * 4 + jj;                 // rope pair index 0..63
        f32x2 cs = *(const f32x2*)&trig[((size_t)s * 64 + i) * 2];
        float e = (float)raw[2 * jj], o = (float)raw[2 * jj + 1];
        qf[kc][2 * jj]     = (__bf16)((e * cs[0] - o * cs[1]) * qscale);
        qf[kc][2 * jj + 1] = (__bf16)((e * cs[1] + o * cs[0]) * qscale);
      }
    }
  }

  f32x4 accO[8] = {};
  float plane = 0.f;
  const int ntile = mb + 1;

  stage_k(0, 0);  // 4 issues

#pragma unroll 1
  for (int t = 0; t < ntile; ++t) {
    const int k0 = t * 64;
    const int cur = t & 1;
    stage_v(k0);                                       // 4 issues
    stage_k(t + 1 < ntile ? k0 + 64 : 0, cur ^ 1);     // 4 issues (dummy on last)

    // K(t) landed: outstanding = K(t)4 + V(t)4 + K(t+1)4 = 12 -> wait to 8
    asm volatile("s_waitcnt vmcnt(8)" ::: "memory");
    __builtin_amdgcn_s_barrier();
    __builtin_amdgcn_sched_barrier(0);

    // ---- QK^T swapped: rows=key, cols=q ----
    f32x4 s2[4] = {};
    __builtin_amdgcn_s_setprio(1);
#pragma unroll
    for (int nt = 0; nt < 4; ++nt)
#pragma unroll
      for (int kc = 0; kc < 4; ++kc) {
        bf16x8 kf = *(const bf16x8*)&Ks[cur][(li + 16 * nt) * 128 +
                                            (((4 * kc + lg) ^ (li & 7)) * 8)];
        s2[nt] = __builtin_amdgcn_mfma_f32_16x16x32_bf16(kf, qf[kc], s2[nt], 0, 0, 0);
      }
    __builtin_amdgcn_s_setprio(0);

    // ---- static-max softmax: p = exp2(s); per-lane partial row-sums ----
    const bool needmask = (k0 + 63 > rbase);
#pragma unroll
    for (int nt = 0; nt < 4; ++nt) {
      bf16x4 pk;
#pragma unroll
      for (int rr = 0; rr < 4; ++rr) {
        const int key = k0 + 16 * nt + lg * 4 + rr;
        float v = s2[nt][rr];
        if (needmask && key > s) v = -INFINITY;
        float p = exp2f(v);
        plane += p;
        pk[rr] = (__bf16)p;
      }
      *(bf16x4*)&Ps[w][li * 72 + 16 * nt + lg * 4] = pk;
    }
    bf16x8 pa[2];
    pa[0] = *(const bf16x8*)&Ps[w][li * 72 + lg * 8];
    pa[1] = *(const bf16x8*)&Ps[w][li * 72 + 32 + lg * 8];

    // V(t) landed: outstanding = V(t)4 + K(t+1)4 = 8 -> wait to 4
    asm volatile("s_waitcnt vmcnt(4)" ::: "memory");
    __builtin_amdgcn_s_barrier();
    __builtin_amdgcn_sched_barrier(0);

    // ---- PV ----
    __builtin_amdgcn_s_setprio(1);
#pragma unroll
    for (int dt = 0; dt < 8; ++dt)
#pragma unroll
      for (int kc = 0; kc < 2; ++kc) {
        bf16x8 vf = *(const bf16x8*)&Vs[(li + 16 * dt) * 64 +
                                        (((4 * kc + lg) ^ (li & 7)) * 8)];
        accO[dt] = __builtin_amdgcn_mfma_f32_16x16x32_bf16(pa[kc], vf, accO[dt], 0, 0, 0);
      }
    __builtin_amdgcn_s_setprio(0);

    __builtin_amdgcn_s_barrier();   // readers done before next tile's staging
    __builtin_amdgcn_sched_barrier(0);
  }

  // ---- epilogue: reduce plane over lg-duplicates, normalize, store ----
  {
    float sum = plane;
    sum += __shfl_xor(sum, 16);
    sum += __shfl_xor(sum, 32);     // lanes sharing li hold total for q = rbase+li
    float inv[4];
#pragma unroll
    for (int rr = 0; rr < 4; ++rr) inv[rr] = 1.0f / __shfl(sum, lg * 4 + rr);
#pragma unroll
    for (int dt = 0; dt < 8; ++dt)
#pragma unroll
      for (int rr = 0; rr < 4; ++rr)
        O[(size_t)(rbase + lg * 4 + rr) * 4096 + h * 128 + dt * 16 + li] =
            (__bf16)(accO[dt][rr] * inv[rr]);
  }
}

// ---------------------------------------------------------------------------
extern "C" void kernel_launch(void* const* d_in, const int* in_sizes, int n_in,
                              void* d_out, int out_size, void* d_ws, size_t ws_size,
                              hipStream_t stream) {
  const float* x  = (const float*)d_in[0];
  const float* wq = (const float*)d_in[1];
  const float* wk = (const float*)d_in[2];
  const float* wv = (const float*)d_in[3];
  const float* wo = (const float*)d_in[4];
  float* out = (float*)d_out;

  const int S = 2048, D = 4096;
  char* ws = (char*)d_ws;
  __bf16* xb  = (__bf16*)ws;                      // 16 MB (reused as AOb)
  __bf16* Qb  = (__bf16*)(ws + 16777216);         // 16 MB
  __bf16* KVb = (__bf16*)(ws + 33554432);         //  8 MB [2048][2048] K|V
  __bf16* Vt  = (__bf16*)(ws + 41943040);         //  4 MB [1024][2048]
  __bf16* wb  = (__bf16*)(ws + 46137344);         // 32 MB weight scratch
  float*  trig = (float*)(ws + 79691776);         //  1 MB
  __bf16* AOb = xb;

  cvt_f32_bf16<<<(S * D / 8 + 255) / 256, 256, 0, stream>>>(x, xb, S * D / 8);
  cvt_f32_bf16<<<(D * D / 8 + 255) / 256, 256, 0, stream>>>(wq, wb, D * D / 8);
  gemm_bf16<128, 128, __bf16><<<dim3(16, 32), 256, 0, stream>>>(
      xb, wb, wb, 1 << 30, Qb, S, D, D);

  cvt_f32_bf16<<<(1024 * D / 8 + 255) / 256, 256, 0, stream>>>(wk, wb, 1024 * D / 8);
  cvt_f32_bf16<<<(1024 * D / 8 + 255) / 256, 256, 0, stream>>>(wv, wb + (size_t)1024 * D,
                                                               1024 * D / 8);
  gemm_bf16<64, 128, __bf16><<<dim3(32, 16), 256, 0, stream>>>(
      xb, wb, wb + (size_t)1024 * D, 1024, KVb, S, 2048, D);

  build_trig<<<(2048 * 64 + 255) / 256, 256, 0, stream>>>(trig);
  // K-rope only; Q-rope is folded into the attention prologue.
  rope_bf16<<<(S * 8 * 64 + 255) / 256, 256, 0, stream>>>(KVb, trig, 2048, 7, 3,
                                                          1.0f, S * 8 * 64);
  transpose_v<<<dim3(32, 16), 256, 0, stream>>>(KVb, Vt);

  attn_fwd_v7<<<1024, 256, 0, stream>>>(Qb, KVb, Vt, trig, AOb);

  cvt_f32_bf16<<<(D * D / 8 + 255) / 256, 256, 0, stream>>>(wo, wb, D * D / 8);
  gemm_bf16<128, 128, float><<<dim3(16, 32), 256, 0, stream>>>(
      AOb, wb, wb, 1 << 30, out, S, D, D);
}

// Round 12
// 344.611 us; speedup vs baseline: 1.1664x; 1.0001x over previous
//
#include <hip/hip_runtime.h>
#include <hip/hip_bf16.h>

typedef float f32x2 __attribute__((ext_vector_type(2)));
typedef float f32x4 __attribute__((ext_vector_type(4)));
typedef __bf16 bf16x4 __attribute__((ext_vector_type(4)));
typedef __bf16 bf16x8 __attribute__((ext_vector_type(8)));

__device__ __forceinline__ void gld_lds16(const void* g, void* l) {
  __builtin_amdgcn_global_load_lds((const __attribute__((address_space(1))) void*)g,
                                   (__attribute__((address_space(3))) void*)l, 16, 0, 0);
}

// ---------------------------------------------------------------------------
__global__ void cvt_f32_bf16(const float* __restrict__ in, __bf16* __restrict__ out,
                             int n8) {
  int idx = blockIdx.x * blockDim.x + threadIdx.x;
  if (idx >= n8) return;
  f32x4 a = *(const f32x4*)(in + (size_t)idx * 8);
  f32x4 b = *(const f32x4*)(in + (size_t)idx * 8 + 4);
  bf16x8 o;
#pragma unroll
  for (int j = 0; j < 4; ++j) { o[j] = (__bf16)a[j]; o[4 + j] = (__bf16)b[j]; }
  *(bf16x8*)(out + (size_t)idx * 8) = o;
}

// ---------------------------------------------------------------------------
__global__ void build_trig(float* __restrict__ trig) {
  int idx = blockIdx.x * blockDim.x + threadIdx.x;
  if (idx >= 2048 * 64) return;
  int i = idx & 63, s = idx >> 6;
  float ang = (float)s * powf(10000.0f, -(float)i * (1.0f / 64.0f));
  float sn, cs;
  sincosf(ang, &sn, &cs);
  trig[idx * 2] = cs;
  trig[idx * 2 + 1] = sn;
}

// ---------------------------------------------------------------------------
// GEMM  C[M][N] = A[M][K] @ B[N][K]^T, bf16 in, OutT out.  (R7-proven
// 128-class 2-barrier structure.)  KVF=true specializes the epilogue for
// the fused KV projection: K-blocks (n0<1024) apply RoPE in-register
// (pairs live in lanes li / li^1 -> one shfl_xor) before writing KVb;
// V-blocks (n0>=1024) write C transposed into Vt[d][s] as b64 packs.
// ---------------------------------------------------------------------------
template <int BM, int BN, typename OutT, bool KVF>
__global__ __launch_bounds__(256) void gemm_bf16(const __bf16* __restrict__ A,
                                                 const __bf16* __restrict__ B0,
                                                 const __bf16* __restrict__ B1,
                                                 int Nsplit, OutT* __restrict__ C,
                                                 int M, int N, int K,
                                                 const float* __restrict__ trig,
                                                 __bf16* __restrict__ Vt) {
  constexpr int MI = BM / 32, NJ = BN / 32;
  constexpr int RA = BM / 32, RB = BN / 32;
  __shared__ __bf16 As[BM * 64] __attribute__((aligned(16)));
  __shared__ __bf16 Bs[BN * 64] __attribute__((aligned(16)));

  const int tid = threadIdx.x;
  const int lane = tid & 63;
  const int w = tid >> 6;
  const int nwg = gridDim.x * gridDim.y;
  const int orig = blockIdx.y * gridDim.x + blockIdx.x;
  const int wgid = (orig & 7) * (nwg >> 3) + (orig >> 3);
  const int m0 = (wgid % gridDim.x) * BM;
  const int n0 = (wgid / gridDim.x) * BN;
  const int li = lane & 15, lg = lane >> 4;

  const __bf16* bsrc[RB];
#pragma unroll
  for (int i = 0; i < RB; ++i) {
    int slot = i * 256 + w * 64 + lane;
    int row = slot >> 3;
    int sch = (slot & 7) ^ (row & 7);
    int n = n0 + row;
    bsrc[i] = (n < Nsplit ? B0 + (size_t)n * K : B1 + (size_t)(n - Nsplit) * K) +
              sch * 8;
  }
  const __bf16* asrc[RA];
#pragma unroll
  for (int i = 0; i < RA; ++i) {
    int slot = i * 256 + w * 64 + lane;
    int row = slot >> 3;
    int sch = (slot & 7) ^ (row & 7);
    asrc[i] = A + (size_t)(m0 + row) * K + sch * 8;
  }

  const int wr = (w >> 1) * (BM / 2);
  const int wc = (w & 1) * (BN / 2);

  f32x4 acc[MI][NJ] = {};

  for (int k0 = 0; k0 < K; k0 += 64) {
    __syncthreads();
#pragma unroll
    for (int i = 0; i < RA; ++i)
      gld_lds16(asrc[i] + k0, &As[(i * 256 + w * 64) * 8]);
#pragma unroll
    for (int i = 0; i < RB; ++i)
      gld_lds16(bsrc[i] + k0, &Bs[(i * 256 + w * 64) * 8]);
    __syncthreads();

#pragma unroll
    for (int u = 0; u < 2; ++u) {
      bf16x8 af[MI], bfr[NJ];
#pragma unroll
      for (int mi = 0; mi < MI; ++mi)
        af[mi] = *(const bf16x8*)&As[(wr + mi * 16 + li) * 64 +
                                     (((u * 4 + lg) ^ (li & 7)) * 8)];
#pragma unroll
      for (int nj = 0; nj < NJ; ++nj)
        bfr[nj] = *(const bf16x8*)&Bs[(wc + nj * 16 + li) * 64 +
                                      (((u * 4 + lg) ^ (li & 7)) * 8)];
#pragma unroll
      for (int mi = 0; mi < MI; ++mi)
#pragma unroll
        for (int nj = 0; nj < NJ; ++nj)
          acc[mi][nj] = __builtin_amdgcn_mfma_f32_16x16x32_bf16(af[mi], bfr[nj],
                                                                acc[mi][nj], 0, 0, 0);
    }
  }

  const int crow = lg * 4;
  if (KVF && n0 >= Nsplit) {
    // ---- V: write transposed into Vt[d][s] (b64 packs along s) ----
#pragma unroll
    for (int mi = 0; mi < MI; ++mi)
#pragma unroll
      for (int nj = 0; nj < NJ; ++nj) {
        int d = n0 - Nsplit + wc + nj * 16 + li;
        int sb = m0 + wr + mi * 16 + crow;
        bf16x4 pk;
#pragma unroll
        for (int r = 0; r < 4; ++r) pk[r] = (__bf16)acc[mi][nj][r];
        *(bf16x4*)&Vt[(size_t)d * 2048 + sb] = pk;
      }
  } else if (KVF) {
    // ---- K: in-register RoPE, then write KVb[s][n] ----
#pragma unroll
    for (int mi = 0; mi < MI; ++mi)
#pragma unroll
      for (int nj = 0; nj < NJ; ++nj) {
        int c = n0 + wc + nj * 16 + li;
        int i = (c & 127) >> 1;
        bool even = (c & 1) == 0;
#pragma unroll
        for (int r = 0; r < 4; ++r) {
          int s = m0 + wr + mi * 16 + crow + r;
          float own = acc[mi][nj][r];
          float oth = __shfl_xor(own, 1);
          f32x2 cs = *(const f32x2*)&trig[((size_t)s * 64 + i) * 2];
          float v = even ? (own * cs[0] - oth * cs[1])   // e*cos - o*sin
                         : (oth * cs[1] + own * cs[0]);  // e*sin + o*cos
          C[(size_t)s * N + c] = (OutT)v;
        }
      }
  } else {
#pragma unroll
    for (int mi = 0; mi < MI; ++mi)
#pragma unroll
      for (int nj = 0; nj < NJ; ++nj)
#pragma unroll
        for (int r = 0; r < 4; ++r)
          C[(size_t)(m0 + wr + mi * 16 + crow + r) * N + (n0 + wc + nj * 16 + li)] =
              (OutT)acc[mi][nj][r];
  }
}

// ---------------------------------------------------------------------------
// Causal GQA flash attention v8.
// vs v7: 32-key tiles, K AND V TRIPLE-buffered -> ONE barrier + one counted
// vmcnt(4) per tile (v7 had 3 barriers/64 keys).  Safety: stage at iter t
// writes buf (t+1)%3, whose previous reader was iter t-2; one barrier/iter
// bounds wave stagger to 1 iter, so that reader is done.  LDS 53KB ->
// 2 blocks/CU.  Grid 1024 longest-first; kvh == XCD.  Q-RoPE folded in
// prologue.  Static-max softmax (p = exp2(s), scores bounded).
// ---------------------------------------------------------------------------
__global__ __launch_bounds__(256) void attn_fwd_v8(const __bf16* __restrict__ Q,
                                                   const __bf16* __restrict__ KVb,
                                                   const __bf16* __restrict__ Vt,
                                                   const float* __restrict__ trig,
                                                   __bf16* __restrict__ O) {
  const int tid = threadIdx.x;
  const int lane = tid & 63;
  const int w = tid >> 6;           // 0..3
  const int bid = blockIdx.x;
  const int xcd = bid & 7;
  const int r9 = bid >> 3;          // 0..127
  const int h = xcd * 4 + (r9 & 3);
  const int mb = 31 - (r9 >> 2);    // longest first
  const int kvh = h >> 2;           // == xcd
  const int m0 = mb * 64;
  const int rbase = m0 + w * 16;

  __shared__ __bf16 Ks[3][32 * 128] __attribute__((aligned(16)));  // 24 KB
  __shared__ __bf16 Vs[3][128 * 32] __attribute__((aligned(16)));  // 24 KB
  __shared__ __bf16 Ps[4][16 * 40] __attribute__((aligned(16)));   //  5 KB

  const int li = lane & 15, lg = lane >> 4;
  const float qscale = 0.08838834764831845f * 1.4426950408889634f;

  auto stage_k = [&](int k0, int buf) {
#pragma unroll
    for (int i = 0; i < 2; ++i) {
      int slot = i * 256 + tid;
      int row = slot >> 4;                 // 0..31 key
      int sch = (slot & 15) ^ (row & 7);
      gld_lds16(&KVb[(size_t)(k0 + row) * 2048 + kvh * 128 + sch * 8],
                &Ks[buf][(i * 256 + w * 64) * 8]);
    }
  };
  auto stage_v = [&](int k0, int buf) {
#pragma unroll
    for (int i = 0; i < 2; ++i) {
      int slot = i * 256 + tid;
      int row = slot >> 2;                 // 0..127 d
      int sch = (slot & 3) ^ (row & 3);
      gld_lds16(&Vt[(size_t)(kvh * 128 + row) * 2048 + k0 + sch * 8],
                &Vs[buf][(i * 256 + w * 64) * 8]);
    }
  };

  // ---- prologue: Q load + in-register RoPE + scale (lane q-row s=rbase+li)
  const int s = rbase + li;
  bf16x8 qf[4];
  {
    const __bf16* qrow = Q + (size_t)s * 4096 + h * 128;
#pragma unroll
    for (int kc = 0; kc < 4; ++kc) {
      bf16x8 raw = *(const bf16x8*)(qrow + kc * 32 + lg * 8);
#pragma unroll
      for (int jj = 0; jj < 4; ++jj) {
        int i = kc * 16 + lg * 4 + jj;
        f32x2 cs = *(const f32x2*)&trig[((size_t)s * 64 + i) * 2];
        float e = (float)raw[2 * jj], o = (float)raw[2 * jj + 1];
        qf[kc][2 * jj]     = (__bf16)((e * cs[0] - o * cs[1]) * qscale);
        qf[kc][2 * jj + 1] = (__bf16)((e * cs[1] + o * cs[0]) * qscale);
      }
    }
  }

  f32x4 accO[8] = {};
  float plane = 0.f;
  const int ntile = 2 * (mb + 1);   // 32-key tiles through the diagonal block

  stage_v(0, 0);
  stage_k(0, 0);                    // 4 issues (tile 0)

#pragma unroll 1
  for (int t = 0; t < ntile; ++t) {
    const int k0 = t * 32;
    const int cb = t % 3;
    const int nk = (t + 1 < ntile) ? k0 + 32 : k0;   // dummy keeps FIFO uniform
    stage_v(nk, (t + 1) % 3);
    stage_k(nk, (t + 1) % 3);       // 4 issues (tile t+1)

    // tile t's 4 landed (8 outstanding -> leave the newest 4)
    asm volatile("s_waitcnt vmcnt(4)" ::: "memory");
    __builtin_amdgcn_s_barrier();
    __builtin_amdgcn_sched_barrier(0);

    // ---- QK^T swapped: rows=key, cols=q ----
    f32x4 s2[2] = {};
    __builtin_amdgcn_s_setprio(1);
#pragma unroll
    for (int nt = 0; nt < 2; ++nt)
#pragma unroll
      for (int kc = 0; kc < 4; ++kc) {
        bf16x8 kf = *(const bf16x8*)&Ks[cb][(li + 16 * nt) * 128 +
                                           (((4 * kc + lg) ^ (li & 7)) * 8)];
        s2[nt] = __builtin_amdgcn_mfma_f32_16x16x32_bf16(kf, qf[kc], s2[nt], 0, 0, 0);
      }
    __builtin_amdgcn_s_setprio(0);

    // ---- static-max softmax ----
    const bool needmask = (k0 + 31 > rbase);
#pragma unroll
    for (int nt = 0; nt < 2; ++nt) {
      bf16x4 pk;
#pragma unroll
      for (int rr = 0; rr < 4; ++rr) {
        const int key = k0 + 16 * nt + lg * 4 + rr;
        float v = s2[nt][rr];
        if (needmask && key > s) v = -INFINITY;
        float p = exp2f(v);
        plane += p;
        pk[rr] = (__bf16)p;
      }
      *(bf16x4*)&Ps[w][li * 40 + 16 * nt + lg * 4] = pk;
    }
    bf16x8 pa = *(const bf16x8*)&Ps[w][li * 40 + lg * 8];

    // ---- PV (K=32: single A-frag) ----
    __builtin_amdgcn_s_setprio(1);
#pragma unroll
    for (int dt = 0; dt < 8; ++dt) {
      bf16x8 vf = *(const bf16x8*)&Vs[cb][(li + 16 * dt) * 32 +
                                          ((lg ^ (li & 3)) * 8)];
      accO[dt] = __builtin_amdgcn_mfma_f32_16x16x32_bf16(pa, vf, accO[dt], 0, 0, 0);
    }
    __builtin_amdgcn_s_setprio(0);
  }

  // ---- epilogue: reduce plane over lg-duplicates, normalize, store ----
  {
    float sum = plane;
    sum += __shfl_xor(sum, 16);
    sum += __shfl_xor(sum, 32);
    float inv[4];
#pragma unroll
    for (int rr = 0; rr < 4; ++rr) inv[rr] = 1.0f / __shfl(sum, lg * 4 + rr);
#pragma unroll
    for (int dt = 0; dt < 8; ++dt)
#pragma unroll
      for (int rr = 0; rr < 4; ++rr)
        O[(size_t)(rbase + lg * 4 + rr) * 4096 + h * 128 + dt * 16 + li] =
            (__bf16)(accO[dt][rr] * inv[rr]);
  }
}

// ---------------------------------------------------------------------------
extern "C" void kernel_launch(void* const* d_in, const int* in_sizes, int n_in,
                              void* d_out, int out_size, void* d_ws, size_t ws_size,
                              hipStream_t stream) {
  const float* x  = (const float*)d_in[0];
  const float* wq = (const float*)d_in[1];
  const float* wk = (const float*)d_in[2];
  const float* wv = (const float*)d_in[3];
  const float* wo = (const float*)d_in[4];
  float* out = (float*)d_out;

  const int S = 2048, D = 4096;
  char* ws = (char*)d_ws;
  __bf16* xb  = (__bf16*)ws;                      // 16 MB (reused as AOb)
  __bf16* Qb  = (__bf16*)(ws + 16777216);         // 16 MB
  __bf16* KVb = (__bf16*)(ws + 33554432);         //  8 MB [2048][2048]; K in cols 0..1023
  __bf16* Vt  = (__bf16*)(ws + 41943040);         //  4 MB [1024][2048]
  __bf16* wb  = (__bf16*)(ws + 46137344);         // 32 MB weight scratch
  float*  trig = (float*)(ws + 79691776);         //  1 MB
  __bf16* AOb = xb;

  cvt_f32_bf16<<<(S * D / 8 + 255) / 256, 256, 0, stream>>>(x, xb, S * D / 8);
  cvt_f32_bf16<<<(D * D / 8 + 255) / 256, 256, 0, stream>>>(wq, wb, D * D / 8);
  gemm_bf16<128, 128, __bf16, false><<<dim3(16, 32), 256, 0, stream>>>(
      xb, wb, wb, 1 << 30, Qb, S, D, D, nullptr, nullptr);

  build_trig<<<(2048 * 64 + 255) / 256, 256, 0, stream>>>(trig);

  cvt_f32_bf16<<<(1024 * D / 8 + 255) / 256, 256, 0, stream>>>(wk, wb, 1024 * D / 8);
  cvt_f32_bf16<<<(1024 * D / 8 + 255) / 256, 256, 0, stream>>>(wv, wb + (size_t)1024 * D,
                                                               1024 * D / 8);
  // KV projection with fused epilogue: K-RoPE in-register, V written transposed.
  gemm_bf16<64, 128, __bf16, true><<<dim3(32, 16), 256, 0, stream>>>(
      xb, wb, wb + (size_t)1024 * D, 1024, KVb, S, 2048, D, trig, Vt);

  attn_fwd_v8<<<1024, 256, 0, stream>>>(Qb, KVb, Vt, trig, AOb);

  cvt_f32_bf16<<<(D * D / 8 + 255) / 256, 256, 0, stream>>>(wo, wb, D * D / 8);
  gemm_bf16<128, 128, float, false><<<dim3(16, 32), 256, 0, stream>>>(
      AOb, wb, wb, 1 << 30, out, S, D, D, nullptr, nullptr);
}